// Round 5
// baseline (83.524 us; speedup 1.0000x reference)
//
#include <hip/hip_runtime.h>

// Problem constants (fixed by the reference): C_IN=8, C_OUT=32, N_RINGS=2,
// WIDTH=4.0, sigma=4.0, rings={0,4}. n and B derived at runtime.
// batch is SORTED -> each graph's points are a contiguous index range.

// One recursive-halving reduce-scatter stage with LITERAL constants so every
// v[] index is compile-time constant (keeps v[] in VGPRs — runtime indexing
// demotes the array to scratch: round-0 showed VGPR=68 / VALUBusy 0.25%).
#define RS_STAGE(M, HALF)                                   \
  {                                                         \
    const bool hi_ = (lane & (M)) != 0;                     \
    _Pragma("unroll")                                       \
    for (int k = 0; k < (HALF); ++k) {                      \
      float send = hi_ ? v[k] : v[(HALF) + k];              \
      float keep = hi_ ? v[(HALF) + k] : v[k];              \
      v[k] = keep + __shfl_xor(send, (M), 64);              \
    }                                                       \
  }

// After all 6 stages, v[0] = sum over the wave's lanes of original component
// rev6(lane), where rev6 is the 6-bit bit-reversal.
#define RS_ALL()     \
  RS_STAGE(1, 32)    \
  RS_STAGE(2, 16)    \
  RS_STAGE(4, 8)     \
  RS_STAGE(8, 4)     \
  RS_STAGE(16, 2)    \
  RS_STAGE(32, 1)

__device__ __forceinline__ int rev6(int l) {
  return ((l & 1) << 5) | ((l & 2) << 3) | ((l & 4) << 1) |
         ((l & 8) >> 1) | ((l & 16) >> 3) | ((l & 32) >> 5);
}

__device__ __forceinline__ void basis8(float rx, float ry, float rz,
                                       float* bas) {
  float d2 = rx * rx + ry * ry + rz * rz;
  float d = sqrtf(d2);
  // rings = {0, 4}, sigma = 4
  float r0 = __expf(-0.03125f * d2);          // exp(-0.5*(d/4)^2)
  float tt = (d - 4.0f) * 0.25f;
  float r1 = __expf(-0.5f * tt * tt);
  float idm = 1.0f / fmaxf(d, 1e-6f);
  float ax = rx * idm, ay = ry * idm, az = rz * idm;
  bas[0] = r0; bas[1] = r0 * ax; bas[2] = r0 * ay; bas[3] = r0 * az;
  bas[4] = r1; bas[5] = r1 * ax; bas[6] = r1 * ay; bas[7] = r1 * az;
}

// ---------- kernel 1: graph boundaries from sorted batch + zero stats -------
// start[g] = first index i with batch[i] >= g; start[B] = n. Handles empty
// graphs (consecutive equal start values).
__global__ __launch_bounds__(256) void boundary_kernel(
    const int* __restrict__ batch, int* __restrict__ start,
    float* __restrict__ stats, int n, int B) {
  int i = blockIdx.x * blockDim.x + threadIdx.x;
  if (i < 64) stats[i] = 0.0f;
  if (i == 0) {
    int b0 = batch[0];
    for (int g = 0; g <= b0; ++g) start[g] = 0;
  }
  if (i < n - 1) {
    int a = batch[i], b = batch[i + 1];
    for (int g = a + 1; g <= b; ++g) start[g] = i + 1;
  } else if (i == n - 1) {
    int a = batch[n - 1];
    for (int g = a + 1; g <= B; ++g) start[g] = n;
  }
}

// ---------- kernel 2: one 512-thread block per graph --------------------
// point-per-thread; coords AND x cached in registers across the mean
// reduction (single global read of each). Tail loop only if cnt > 512.
__global__ __launch_bounds__(512, 4) void graph_kernel(
    const float* __restrict__ x, const float* __restrict__ coords,
    const int* __restrict__ start, const float* __restrict__ W,
    float* __restrict__ out_raw, float* __restrict__ stats, int n) {
  __shared__ float sredm[8][3];   // per-wave coord sums
  __shared__ float sred[8][64];   // per-wave V partials
  __shared__ float sVg[64];       // aggregated V
  __shared__ float pre2[4][32];   // GEMM partials
  __shared__ float smean[3];

  const int g = blockIdx.x;
  const int lo = start[g], hi = start[g + 1];
  const int cnt = hi - lo;
  const int t = threadIdx.x;
  const int lane = t & 63;
  const int wv = t >> 6;

  // ---- issue all primary loads up front (latency hides under reduction) ----
  const int i0 = lo + t;
  const bool valid0 = t < cnt;
  const int ic = min(i0, n - 1);
  float cx = coords[(size_t)ic * 3 + 0];
  float cy = coords[(size_t)ic * 3 + 1];
  float cz = coords[(size_t)ic * 3 + 2];
  float4 xa = ((const float4*)x)[2 * (size_t)ic];
  float4 xb = ((const float4*)x)[2 * (size_t)ic + 1];

  // ---- pass 1: mean of coords ----
  float s1 = valid0 ? cx : 0.f;
  float s2 = valid0 ? cy : 0.f;
  float s3 = valid0 ? cz : 0.f;
  for (int i = lo + 512 + t; i < hi; i += 512) {   // rare tail
    s1 += coords[(size_t)i * 3 + 0];
    s2 += coords[(size_t)i * 3 + 1];
    s3 += coords[(size_t)i * 3 + 2];
  }
#pragma unroll
  for (int m = 1; m < 64; m <<= 1) {
    s1 += __shfl_xor(s1, m, 64);
    s2 += __shfl_xor(s2, m, 64);
    s3 += __shfl_xor(s3, m, 64);
  }
  if (lane == 0) { sredm[wv][0] = s1; sredm[wv][1] = s2; sredm[wv][2] = s3; }
  __syncthreads();
  if (t < 3) {
    float a = 0.f;
#pragma unroll
    for (int w = 0; w < 8; ++w) a += sredm[w][t];
    smean[t] = a / (float)max(cnt, 1);
  }
  __syncthreads();
  const float mx = smean[0], my = smean[1], mz = smean[2];

  // ---- pass 2: basis x feature outer product (registers only) ----
  float v[64];
  {
    float bas[8];
    basis8(mx - cx, my - cy, mz - cz, bas);
    float xv[8] = {xa.x, xa.y, xa.z, xa.w, xb.x, xb.y, xb.z, xb.w};
    if (!valid0) {
#pragma unroll
      for (int i8 = 0; i8 < 8; ++i8) xv[i8] = 0.f;
    }
#pragma unroll
    for (int i8 = 0; i8 < 8; ++i8)
#pragma unroll
      for (int b = 0; b < 8; ++b) v[i8 * 8 + b] = xv[i8] * bas[b];
  }
  for (int i = lo + 512 + t; i < hi; i += 512) {   // rare tail
    float ex = coords[(size_t)i * 3 + 0];
    float ey = coords[(size_t)i * 3 + 1];
    float ez = coords[(size_t)i * 3 + 2];
    float bas[8];
    basis8(mx - ex, my - ey, mz - ez, bas);
    float4 ya = ((const float4*)x)[2 * (size_t)i];
    float4 yb = ((const float4*)x)[2 * (size_t)i + 1];
    float xv[8] = {ya.x, ya.y, ya.z, ya.w, yb.x, yb.y, yb.z, yb.w};
#pragma unroll
    for (int i8 = 0; i8 < 8; ++i8)
#pragma unroll
      for (int b = 0; b < 8; ++b) v[i8 * 8 + b] += xv[i8] * bas[b];
  }

  // ---- wave reduce-scatter + cross-wave combine ----
  RS_ALL();
  sred[wv][rev6(lane)] = v[0];
  __syncthreads();
  if (t < 64) {
    float a = 0.f;
#pragma unroll
    for (int w = 0; w < 8; ++w) a += sred[w][t];
    sVg[t] = a;
  }
  __syncthreads();

  // ---- per-graph GEMM: out[o] = sum_k Vg[k] * W[o*64+k] (threads 0..255) ----
  if (t < 256) {
    const int o = t & 31;
    const int part = t >> 5;            // 0..7, k-chunks of 8
    const float* wrow = W + (size_t)o * 64 + part * 8;
    float4 w0 = *(const float4*)(wrow);
    float4 w1 = *(const float4*)(wrow + 4);
    float4 v0 = *(const float4*)(&sVg[part * 8]);
    float4 v1 = *(const float4*)(&sVg[part * 8 + 4]);
    float r = w0.x * v0.x + w0.y * v0.y + w0.z * v0.z + w0.w * v0.w +
              w1.x * v1.x + w1.y * v1.y + w1.z * v1.z + w1.w * v1.w;
    r += __shfl_xor(r, 32, 64);         // combine part pairs within wave
    if (lane < 32) pre2[wv][o] = r;
  }
  __syncthreads();
  if (t < 32) {
    float outv = pre2[0][t] + pre2[1][t] + pre2[2][t] + pre2[3][t];
    out_raw[(size_t)g * 32 + t] = outv;
    atomicAdd(&stats[t], outv);
    atomicAdd(&stats[32 + t], outv * outv);
  }
}

// ---------- kernel 3: batchnorm + relu(|.|-bias) ----------
__global__ __launch_bounds__(256) void final_kernel(
    const float* __restrict__ out_raw, const float* __restrict__ stats,
    const float* __restrict__ gamma, const float* __restrict__ beta,
    const float* __restrict__ act_bias, float* __restrict__ out, int B) {
  int t = blockIdx.x * blockDim.x + threadIdx.x;
  if (t >= B * 32) return;
  int o = t & 31;
  float invB = 1.0f / (float)B;
  float mu = stats[o] * invB;
  float var = stats[32 + o] * invB - mu * mu;
  float xn = (out_raw[t] - mu) * rsqrtf(var + 1e-5f) * gamma[o] + beta[o];
  float y = fabsf(xn) - act_bias[o];
  out[t] = fmaxf(y, 0.0f);
}

extern "C" void kernel_launch(void* const* d_in, const int* in_sizes, int n_in,
                              void* d_out, int out_size, void* d_ws, size_t ws_size,
                              hipStream_t stream) {
  const float* x      = (const float*)d_in[0];
  const float* coords = (const float*)d_in[1];
  const int*   batch  = (const int*)d_in[2];
  const float* W      = (const float*)d_in[3];
  const float* gamma  = (const float*)d_in[4];
  const float* beta   = (const float*)d_in[5];
  const float* abias  = (const float*)d_in[6];
  float* out = (float*)d_out;

  int n = in_sizes[2];          // N points
  int B = out_size / 32;        // graphs

  // ws layout: start[B+1] ints | pad | stats[64] floats | out_raw[B*32] floats
  int*   start     = (int*)d_ws;
  int    stats_off = ((B + 1 + 3) / 4) * 4;        // 16B-align
  float* stats     = (float*)d_ws + stats_off;
  float* out_raw   = stats + 64;

  boundary_kernel<<<(n + 255) / 256, 256, 0, stream>>>(batch, start, stats, n, B);
  graph_kernel<<<B, 512, 0, stream>>>(x, coords, start, W, out_raw, stats, n);
  final_kernel<<<(B * 32 + 255) / 256, 256, 0, stream>>>(out_raw, stats, gamma, beta, abias, out, B);
}

// Round 6
// 83.177 us; speedup vs baseline: 1.0042x; 1.0042x over previous
//
#include <hip/hip_runtime.h>

// Problem constants (fixed by the reference): C_IN=8, C_OUT=32, N_RINGS=2,
// WIDTH=4.0, sigma=4.0, rings={0,4}. n and B derived at runtime.
// batch is SORTED -> each graph's points are a contiguous index range.
//
// Hard-won config notes (do not regress):
//  * graph_kernel MUST be 256 threads + plain __launch_bounds__(256).
//    Round 5 used __launch_bounds__(512,4) -> VGPR cap 128 -> v[64] spilled
//    to scratch (VGPR_Count=52, VALUBusy 12.5%, 74 us). Round 0 same disease.
//  * v[] must only ever be indexed with compile-time constants.

// One recursive-halving reduce-scatter stage with LITERAL constants so every
// v[] index is compile-time constant.
#define RS_STAGE(M, HALF)                                   \
  {                                                         \
    const bool hi_ = (lane & (M)) != 0;                     \
    _Pragma("unroll")                                       \
    for (int k = 0; k < (HALF); ++k) {                      \
      float send = hi_ ? v[k] : v[(HALF) + k];              \
      float keep = hi_ ? v[(HALF) + k] : v[k];              \
      v[k] = keep + __shfl_xor(send, (M), 64);              \
    }                                                       \
  }

// After all 6 stages, v[0] = sum over the wave's lanes of original component
// rev6(lane), where rev6 is the 6-bit bit-reversal.
#define RS_ALL()     \
  RS_STAGE(1, 32)    \
  RS_STAGE(2, 16)    \
  RS_STAGE(4, 8)     \
  RS_STAGE(8, 4)     \
  RS_STAGE(16, 2)    \
  RS_STAGE(32, 1)

__device__ __forceinline__ int rev6(int l) {
  return ((l & 1) << 5) | ((l & 2) << 3) | ((l & 4) << 1) |
         ((l & 8) >> 1) | ((l & 16) >> 3) | ((l & 32) >> 5);
}

__device__ __forceinline__ void basis8(float rx, float ry, float rz,
                                       float* bas) {
  float d2 = rx * rx + ry * ry + rz * rz;
  float d = sqrtf(d2);
  // rings = {0, 4}, sigma = 4
  float r0 = __expf(-0.03125f * d2);          // exp(-0.5*(d/4)^2)
  float tt = (d - 4.0f) * 0.25f;
  float r1 = __expf(-0.5f * tt * tt);
  float idm = 1.0f / fmaxf(d, 1e-6f);
  float ax = rx * idm, ay = ry * idm, az = rz * idm;
  bas[0] = r0; bas[1] = r0 * ax; bas[2] = r0 * ay; bas[3] = r0 * az;
  bas[4] = r1; bas[5] = r1 * ax; bas[6] = r1 * ay; bas[7] = r1 * az;
}

// ---------- kernel 1: graph boundaries from sorted batch + zero stats -------
// start[g] = first index i with batch[i] >= g; start[B] = n. Handles empty
// graphs (consecutive equal start values).
__global__ __launch_bounds__(256) void boundary_kernel(
    const int* __restrict__ batch, int* __restrict__ start,
    float* __restrict__ stats, int n, int B) {
  int i = blockIdx.x * blockDim.x + threadIdx.x;
  if (i < 64) stats[i] = 0.0f;
  if (i == 0) {
    int b0 = batch[0];
    for (int g = 0; g <= b0; ++g) start[g] = 0;
  }
  if (i < n - 1) {
    int a = batch[i], b = batch[i + 1];
    for (int g = a + 1; g <= b; ++g) start[g] = i + 1;
  } else if (i == n - 1) {
    int a = batch[n - 1];
    for (int g = a + 1; g <= B; ++g) start[g] = n;
  }
}

// ---------- kernel 2: one 256-thread block per graph ------------------------
// Two point-strips (up to 512 points) register-cached in pass 1 so pass 2 is
// pure VALU; tail loop only if cnt > 512 (prob ~0 at N/B = 488, but correct).
// Fused per-channel stats atomics at the end (stats pre-zeroed by kernel 1).
__global__ __launch_bounds__(256) void graph_kernel(
    const float* __restrict__ x, const float* __restrict__ coords,
    const int* __restrict__ start, const float* __restrict__ W,
    float* __restrict__ out_raw, float* __restrict__ stats, int n) {
  __shared__ float sredm[4][3];   // per-wave coord sums
  __shared__ float sred[4][64];   // per-wave V partials
  __shared__ float sVg[64];       // aggregated V
  __shared__ float pre2[4][32];   // GEMM partials
  __shared__ float smean[3];

  const int g = blockIdx.x;
  const int lo = start[g], hi = start[g + 1];
  const int cnt = hi - lo;
  const int t = threadIdx.x;
  const int lane = t & 63;
  const int wv = t >> 6;

  // ---- issue all primary loads up front; cache in registers ----
  const bool vA = t < cnt;
  const bool vB = 256 + t < cnt;
  const int iA = min(lo + t, n - 1);
  const int iB = min(lo + 256 + t, n - 1);
  float cAx = coords[(size_t)iA * 3 + 0];
  float cAy = coords[(size_t)iA * 3 + 1];
  float cAz = coords[(size_t)iA * 3 + 2];
  float cBx = coords[(size_t)iB * 3 + 0];
  float cBy = coords[(size_t)iB * 3 + 1];
  float cBz = coords[(size_t)iB * 3 + 2];
  float4 xA0 = ((const float4*)x)[2 * (size_t)iA];
  float4 xA1 = ((const float4*)x)[2 * (size_t)iA + 1];
  float4 xB0 = ((const float4*)x)[2 * (size_t)iB];
  float4 xB1 = ((const float4*)x)[2 * (size_t)iB + 1];

  // ---- pass 1: mean of coords ----
  float s1 = (vA ? cAx : 0.f) + (vB ? cBx : 0.f);
  float s2 = (vA ? cAy : 0.f) + (vB ? cBy : 0.f);
  float s3 = (vA ? cAz : 0.f) + (vB ? cBz : 0.f);
  for (int i = lo + 512 + t; i < hi; i += 256) {   // rare tail
    s1 += coords[(size_t)i * 3 + 0];
    s2 += coords[(size_t)i * 3 + 1];
    s3 += coords[(size_t)i * 3 + 2];
  }
#pragma unroll
  for (int m = 1; m < 64; m <<= 1) {
    s1 += __shfl_xor(s1, m, 64);
    s2 += __shfl_xor(s2, m, 64);
    s3 += __shfl_xor(s3, m, 64);
  }
  if (lane == 0) { sredm[wv][0] = s1; sredm[wv][1] = s2; sredm[wv][2] = s3; }
  __syncthreads();
  if (t < 3) {
    smean[t] = (sredm[0][t] + sredm[1][t] + sredm[2][t] + sredm[3][t]) /
               (float)max(cnt, 1);
  }
  __syncthreads();
  const float mx = smean[0], my = smean[1], mz = smean[2];

  // ---- pass 2: basis x feature outer product (registers only) ----
  float v[64];
  {
    float bas[8];
    basis8(mx - cAx, my - cAy, mz - cAz, bas);
    float xv[8] = {xA0.x, xA0.y, xA0.z, xA0.w, xA1.x, xA1.y, xA1.z, xA1.w};
    if (!vA) {
#pragma unroll
      for (int i8 = 0; i8 < 8; ++i8) xv[i8] = 0.f;
    }
#pragma unroll
    for (int i8 = 0; i8 < 8; ++i8)
#pragma unroll
      for (int b = 0; b < 8; ++b) v[i8 * 8 + b] = xv[i8] * bas[b];
  }
  if (cnt > 256) {                                 // block-uniform branch
    float bas[8];
    basis8(mx - cBx, my - cBy, mz - cBz, bas);
    float xv[8] = {xB0.x, xB0.y, xB0.z, xB0.w, xB1.x, xB1.y, xB1.z, xB1.w};
    if (!vB) {
#pragma unroll
      for (int i8 = 0; i8 < 8; ++i8) xv[i8] = 0.f;
    }
#pragma unroll
    for (int i8 = 0; i8 < 8; ++i8)
#pragma unroll
      for (int b = 0; b < 8; ++b) v[i8 * 8 + b] += xv[i8] * bas[b];
  }
  for (int i = lo + 512 + t; i < hi; i += 256) {   // rare tail: reload
    float ex = coords[(size_t)i * 3 + 0];
    float ey = coords[(size_t)i * 3 + 1];
    float ez = coords[(size_t)i * 3 + 2];
    float bas[8];
    basis8(mx - ex, my - ey, mz - ez, bas);
    float4 ya = ((const float4*)x)[2 * (size_t)i];
    float4 yb = ((const float4*)x)[2 * (size_t)i + 1];
    float xv[8] = {ya.x, ya.y, ya.z, ya.w, yb.x, yb.y, yb.z, yb.w};
#pragma unroll
    for (int i8 = 0; i8 < 8; ++i8)
#pragma unroll
      for (int b = 0; b < 8; ++b) v[i8 * 8 + b] += xv[i8] * bas[b];
  }

  // ---- wave reduce-scatter + cross-wave combine ----
  RS_ALL();
  sred[wv][rev6(lane)] = v[0];
  __syncthreads();
  if (t < 64) sVg[t] = sred[0][t] + sred[1][t] + sred[2][t] + sred[3][t];
  __syncthreads();

  // ---- per-graph GEMM: out[o] = sum_k Vg[k] * W[o*64+k] ----
  const int o = t & 31;
  const int part = t >> 5;              // 0..7, k-chunks of 8
  const float* wrow = W + (size_t)o * 64 + part * 8;
  float4 w0 = *(const float4*)(wrow);
  float4 w1 = *(const float4*)(wrow + 4);
  float4 v0 = *(const float4*)(&sVg[part * 8]);
  float4 v1 = *(const float4*)(&sVg[part * 8 + 4]);
  float r = w0.x * v0.x + w0.y * v0.y + w0.z * v0.z + w0.w * v0.w +
            w1.x * v1.x + w1.y * v1.y + w1.z * v1.z + w1.w * v1.w;
  r += __shfl_xor(r, 32, 64);           // combine part pairs within wave
  if (lane < 32) pre2[wv][o] = r;
  __syncthreads();
  if (t < 32) {
    float outv = pre2[0][t] + pre2[1][t] + pre2[2][t] + pre2[3][t];
    out_raw[(size_t)g * 32 + t] = outv;
    atomicAdd(&stats[t], outv);
    atomicAdd(&stats[32 + t], outv * outv);
  }
}

// ---------- kernel 3: batchnorm + relu(|.|-bias) ----------
__global__ __launch_bounds__(256) void final_kernel(
    const float* __restrict__ out_raw, const float* __restrict__ stats,
    const float* __restrict__ gamma, const float* __restrict__ beta,
    const float* __restrict__ act_bias, float* __restrict__ out, int B) {
  int t = blockIdx.x * blockDim.x + threadIdx.x;
  if (t >= B * 32) return;
  int o = t & 31;
  float invB = 1.0f / (float)B;
  float mu = stats[o] * invB;
  float var = stats[32 + o] * invB - mu * mu;
  float xn = (out_raw[t] - mu) * rsqrtf(var + 1e-5f) * gamma[o] + beta[o];
  float y = fabsf(xn) - act_bias[o];
  out[t] = fmaxf(y, 0.0f);
}

extern "C" void kernel_launch(void* const* d_in, const int* in_sizes, int n_in,
                              void* d_out, int out_size, void* d_ws, size_t ws_size,
                              hipStream_t stream) {
  const float* x      = (const float*)d_in[0];
  const float* coords = (const float*)d_in[1];
  const int*   batch  = (const int*)d_in[2];
  const float* W      = (const float*)d_in[3];
  const float* gamma  = (const float*)d_in[4];
  const float* beta   = (const float*)d_in[5];
  const float* abias  = (const float*)d_in[6];
  float* out = (float*)d_out;

  int n = in_sizes[2];          // N points
  int B = out_size / 32;        // graphs

  // ws layout: start[B+1] ints | pad | stats[64] floats | out_raw[B*32] floats
  int*   start     = (int*)d_ws;
  int    stats_off = ((B + 1 + 3) / 4) * 4;        // 16B-align
  float* stats     = (float*)d_ws + stats_off;
  float* out_raw   = stats + 64;

  boundary_kernel<<<(n + 255) / 256, 256, 0, stream>>>(batch, start, stats, n, B);
  graph_kernel<<<B, 256, 0, stream>>>(x, coords, start, W, out_raw, stats, n);
  final_kernel<<<(B * 32 + 255) / 256, 256, 0, stream>>>(out_raw, stats, gamma, beta, abias, out, B);
}